// Round 9
// baseline (215.537 us; speedup 1.0000x reference)
//
#include <hip/hip_runtime.h>

// Problem constants
#define N_TOK 4096   // H*W
#define C_DIM 256
#define D_DIM 32

typedef float f32x4 __attribute__((ext_vector_type(4)));
typedef short short8 __attribute__((ext_vector_type(8)));
typedef unsigned short u16;

__device__ __forceinline__ u16 f2bf(float f) {
    unsigned int u = __builtin_bit_cast(unsigned int, f);
    u += 0x7fffu + ((u >> 16) & 1u);   // round-to-nearest-even
    return (u16)(u >> 16);
}
__device__ __forceinline__ u16 f2bf_fast(float f) {   // round-half-up (f >= 0)
    return (u16)((__builtin_bit_cast(unsigned int, f) + 0x8000u) >> 16);
}
__device__ __forceinline__ float bf2f(u16 h) {
    unsigned int u = ((unsigned int)h) << 16;
    return __builtin_bit_cast(float, u);
}
__device__ __forceinline__ float exp2_fast(float x) {  // 2^x, compiler-managed
#if __has_builtin(__builtin_amdgcn_exp2f)
    return __builtin_amdgcn_exp2f(x);
#else
    return exp2f(x);
#endif
}

// Packed V layout (bf16 shorts), per slice (1M shorts = 2MB):
//   addr = jblk*8192 + c*32 + pos*8 + (j&7),  jblk = j>>5,
//   pos  = ((j>>3)&3) ^ ((c>>1)&3)            (chunk XOR swizzle baked in)
// A jblk-tile is contiguous 16KB; its c-half [128,256) is a contiguous 8KB.

// ---------------------------------------------------------------------------
// Kernel 1: q/k projection.  q = (wq*x1 + bq)*log2e, k = wk*x2 + bk
// Output layout: Q[slice][i][d], K[slice][j][d]  (d contiguous, bf16)
// ---------------------------------------------------------------------------
__global__ __launch_bounds__(256) void qk_proj(
    const float* __restrict__ x1, const float* __restrict__ x2,
    const float* __restrict__ wq1, const float* __restrict__ bq1,
    const float* __restrict__ wk1, const float* __restrict__ bk1,
    const float* __restrict__ wq2, const float* __restrict__ bq2,
    const float* __restrict__ wk2, const float* __restrict__ bk2,
    u16* __restrict__ wsQ, u16* __restrict__ wsK)
{
    __shared__ float w_lds[32 * 256];
    const int ib = blockIdx.x;
    const int comb = blockIdx.y;
    const int b = comb & 3;
    const int branch = (comb >> 2) & 1;
    const int qk = comb >> 3;

    const float* x = qk ? x2 : x1;           // q from x1; k from x2
    const float* w; const float* bias; u16* dst;
    if (qk == 0) { w = branch ? wq2 : wq1; bias = branch ? bq2 : bq1; dst = wsQ; }
    else         { w = branch ? wk2 : wk1; bias = branch ? bk2 : bk1; dst = wsK; }
    const int slice = branch * 4 + b;
    dst += (size_t)slice * N_TOK * D_DIM;
    const float osc = (qk == 0) ? 1.44269504088896341f : 1.0f;

    const int tid = threadIdx.x;
    for (int t = tid; t < 32 * 256; t += 256) w_lds[t] = w[t];
    __syncthreads();

    const int il = tid & 63;
    const int db = tid >> 6;                 // 0..3 -> d = db*8 + mm
    const float* xc = x + (size_t)b * C_DIM * N_TOK + ib * 64 + il;

    float acc[8] = {0.f,0.f,0.f,0.f,0.f,0.f,0.f,0.f};
    for (int c4 = 0; c4 < 256; c4 += 4) {
        const float xv0 = xc[(size_t)(c4 + 0) * N_TOK];
        const float xv1 = xc[(size_t)(c4 + 1) * N_TOK];
        const float xv2 = xc[(size_t)(c4 + 2) * N_TOK];
        const float xv3 = xc[(size_t)(c4 + 3) * N_TOK];
#pragma unroll
        for (int mm = 0; mm < 8; ++mm) {
            const float4 wv = *(const float4*)&w_lds[(db * 8 + mm) * 256 + c4];
            acc[mm] += xv0 * wv.x + xv1 * wv.y + xv2 * wv.z + xv3 * wv.w;
        }
    }
    short8 pack;
#pragma unroll
    for (int mm = 0; mm < 8; ++mm)
        pack[mm] = (short)f2bf((acc[mm] + bias[db * 8 + mm]) * osc);
    *(short8*)(dst + (size_t)(ib * 64 + il) * D_DIM + db * 8) = pack;
}

// ---------------------------------------------------------------------------
// Kernel 2: v projection via MFMA, writing PACKED V tiles.
// block 256 (4 waves, 2x2 wave grid), tile 128c x 128j, K=256 in 8 steps.
// grid (32 jt, 2 ct, 8 slices)
// ---------------------------------------------------------------------------
__device__ __forceinline__ void stage_xt(u16* xtb, const float* xb, int ks,
                                         int wave, int lane)
{
    // XT[j][k] (32 k per buf, 64B rows), chunk kc stored at pos kc ^ ((j>>1)&3)
    const int j  = (wave & 1) * 64 + lane;
    const int cb = (wave >> 1) * 16;       // k (cin) base, 16 per thread
    const float* xp = xb + (size_t)(ks * 32 + cb) * N_TOK + j;
    u16 vals[16];
#pragma unroll
    for (int qq = 0; qq < 16; ++qq) vals[qq] = f2bf(xp[(size_t)qq * N_TOK]);
    const int swz = (j >> 1) & 3;
    u16* row = xtb + j * 32;
    const int c0 = cb >> 3;
    *(short8*)&row[((c0    ) ^ swz) * 8] = *(const short8*)&vals[0];
    *(short8*)&row[((c0 + 1) ^ swz) * 8] = *(const short8*)&vals[8];
}

__global__ __launch_bounds__(256, 2) void v_proj(
    const float* __restrict__ x2,
    const float* __restrict__ wv1, const float* __restrict__ bv1,
    const float* __restrict__ wv2, const float* __restrict__ bv2,
    u16* __restrict__ wsV)
{
    __shared__ __align__(16) u16 wl[128 * 256];     // [c][k] swizzled, 64 KB
    __shared__ __align__(16) u16 xt[2][128 * 32];   // [j][k] swizzled, 16 KB

    const int jt = blockIdx.x, ct = blockIdx.y, s = blockIdx.z;
    const int branch = s >> 2, b = s & 3;
    const float* w    = branch ? wv2 : wv1;
    const float* bias = branch ? bv2 : bv1;
    u16* dst = wsV + (size_t)s * C_DIM * N_TOK;     // packed slice base
    const float* xb = x2 + (size_t)b * C_DIM * N_TOK + jt * 128;

    const int tid = threadIdx.x;
    const int wave = tid >> 6, lane = tid & 63;
    const int wr = wave >> 1, wc = wave & 1;
    const int g = lane >> 4, li = lane & 15;

    // ---- stage W[128c][256k] -> bf16 LDS, chunk kc at pos kc ^ (c&7)
    {
        const int c = tid >> 1;
        const int kh = (tid & 1) * 128;
        const float* wrow = w + (size_t)(ct * 128 + c) * C_DIM + kh;
        u16* lrow = wl + c * 256;
#pragma unroll
        for (int kk = 0; kk < 128; kk += 8) {
            const float4 a0 = *(const float4*)&wrow[kk];
            const float4 a1 = *(const float4*)&wrow[kk + 4];
            u16 tmp[8] = {f2bf(a0.x), f2bf(a0.y), f2bf(a0.z), f2bf(a0.w),
                          f2bf(a1.x), f2bf(a1.y), f2bf(a1.z), f2bf(a1.w)};
            const int kc = (kh + kk) >> 3;
            *(short8*)&lrow[(kc ^ (c & 7)) * 8] = *(const short8*)tmp;
        }
    }
    stage_xt(&xt[0][0], xb, 0, wave, lane);
    __syncthreads();

    f32x4 acc[4][4];
#pragma unroll
    for (int mf = 0; mf < 4; ++mf)
#pragma unroll
        for (int nf = 0; nf < 4; ++nf) acc[mf][nf] = (f32x4){0.f, 0.f, 0.f, 0.f};

    int buf = 0;
    for (int ks = 0; ks < 8; ++ks) {
        if (ks < 7) stage_xt(&xt[buf ^ 1][0], xb, ks + 1, wave, lane);

        short8 af[4], bf[4];
#pragma unroll
        for (int mf = 0; mf < 4; ++mf) {
            const int c = wr * 64 + mf * 16 + li;
            af[mf] = *(const short8*)&wl[c * 256 + (((ks * 4 + g) ^ (li & 7)) * 8)];
        }
#pragma unroll
        for (int nf = 0; nf < 4; ++nf) {
            const int j = wc * 64 + nf * 16 + li;
            bf[nf] = *(const short8*)&xt[buf][j * 32 + ((g ^ ((j >> 1) & 3)) * 8)];
        }
        __builtin_amdgcn_s_setprio(1);
#pragma unroll
        for (int mf = 0; mf < 4; ++mf)
#pragma unroll
            for (int nf = 0; nf < 4; ++nf)
                acc[mf][nf] = __builtin_amdgcn_mfma_f32_16x16x32_bf16(
                    af[mf], bf[nf], acc[mf][nf], 0, 0, 0);
        __builtin_amdgcn_s_setprio(0);
        __syncthreads();
        buf ^= 1;
    }

    // ---- epilogue: write packed-swizzled tiles
#pragma unroll
    for (int mf = 0; mf < 4; ++mf) {
#pragma unroll
        for (int r = 0; r < 4; ++r) {
            const int c = ct * 128 + wr * 64 + mf * 16 + 4 * g + r;
            const float bv = bias[c];
            const int cswz = (c >> 1) & 3;
            u16* crow = dst + c * 32;
#pragma unroll
            for (int nf = 0; nf < 4; ++nf) {
                const int j = jt * 128 + wc * 64 + nf * 16 + li;
                const int pos = ((j >> 3) & 3) ^ cswz;
                crow[(size_t)(j >> 5) * 8192 + pos * 8 + (j & 7)] =
                    f2bf(acc[mf][nf][r] + bv);
            }
        }
    }
}

// ---------------------------------------------------------------------------
// Kernel 3: flash attention, static-max exp2 softmax, c-split, T3/T4 pipeline.
// block 256 = 4 waves = 2 j-halves (grp) x 2 i-halves (wg); R=2 (32 i/wave);
// each block owns a 128-c half (ct).  acc[2][8] = 64 VGPRs.
// 3 LDS buffers per grp, stage issued 2 periods ahead; K reg-prefetch 2 ahead;
// counted s_waitcnt vmcnt(8) + raw s_barrier (NOT __syncthreads) per period:
// leaves {K(t+1), stage(t+2), K(t+2)} = 8 ops in flight across the barrier,
// guarantees stage(t+1) landed (vmcnt retires in issue order).
// grid 1024: n = slice + 8*(ib + 64*ct); slice = n%8 -> XCD affinity.
// ---------------------------------------------------------------------------
__device__ __forceinline__ void stage_v32c(const u16* vhalf, short* dst,
                                           int wg, int lane, int j0)
{
    const u16* tile = vhalf + (size_t)(j0 >> 5) * 8192;   // contiguous 8KB c-half
#pragma unroll
    for (int ii = 0; ii < 4; ++ii) {
        const int off = (wg * 4 + ii) * 512;              // shorts
        __builtin_amdgcn_global_load_lds(
            (const __attribute__((address_space(1))) void*)(tile + off + lane * 8),
            (__attribute__((address_space(3))) void*)(dst + off), 16, 0, 0);
    }
}

__global__ __launch_bounds__(256, 4) void attn_fwd(
    const u16* __restrict__ Q, const u16* __restrict__ K,
    const u16* __restrict__ V, u16* __restrict__ O)
{
    __shared__ __align__(16) short vlds[2][3][128 * 32];  // [grp][buf] 48 KB
    __shared__ float lscr[2][2][64][2];                   // [grp][wg][lane][it]

    const int n  = blockIdx.x;
    const int s  = n & 7;              // slice -> XCD (n%8)
    const int ib = (n >> 3) & 63;      // i-block of 64 rows
    const int ct = n >> 9;             // c-half
    const u16* q = Q + (size_t)s * N_TOK * D_DIM;
    const u16* k = K + (size_t)s * N_TOK * D_DIM;
    const u16* v = V + (size_t)s * C_DIM * N_TOK + ct * 4096;  // c-half in tile
    u16*       o = O + (size_t)s * N_TOK * C_DIM + ct * 128;

    const int tid  = threadIdx.x;
    const int wave = tid >> 6;
    const int lane = tid & 63;
    const int grp  = wave >> 1;        // j-half
    const int wg   = wave & 1;
    const int g    = lane >> 4;
    const int li   = lane & 15;
    const int i0   = ib * 64 + wg * 32;
    const int jbase = grp * (N_TOK / 2);
    const int NP = N_TOK / 2 / 32;     // 64 periods of 32 j

    short8 qf[2];
    qf[0] = *(const short8*)(q + (size_t)(i0 + li) * D_DIM + 8 * g);
    qf[1] = *(const short8*)(q + (size_t)(i0 + 16 + li) * D_DIM + 8 * g);

    f32x4 acc[2][8];
#pragma unroll
    for (int it = 0; it < 2; ++it)
#pragma unroll
        for (int cf = 0; cf < 8; ++cf) acc[it][cf] = (f32x4){0.f, 0.f, 0.f, 0.f};
    float lsum[2] = {0.f, 0.f};

    const int roff = (g ^ ((li >> 1) & 3)) << 3;   // swizzled chunk offset

    // ---- prologue: stage(0),K(0),stage(1),K(1)  [issue order matters]
    stage_v32c(v, &vlds[grp][0][0], wg, lane, jbase);
    short8 keC = *(const short8*)(k + (size_t)(jbase + 2 * li    ) * D_DIM + 8 * g);
    short8 koC = *(const short8*)(k + (size_t)(jbase + 2 * li + 1) * D_DIM + 8 * g);
    stage_v32c(v, &vlds[grp][1][0], wg, lane, jbase + 32);
    short8 keN = *(const short8*)(k + (size_t)(jbase + 32 + 2 * li) * D_DIM + 8 * g);
    short8 koN = *(const short8*)(k + (size_t)(jbase + 33 + 2 * li) * D_DIM + 8 * g);
    // wait: stage(0) retired (newest 8 = K(0)+stage(1)+K(1) may stay in flight)
    asm volatile("s_waitcnt vmcnt(8)" ::: "memory");
    __builtin_amdgcn_s_barrier();

    int bcur = 0;                       // t % 3
    for (int p = 0; p < NP; ++p) {
        // issue stage(t+2) + K(t+2)  (wrap harmlessly at the tail)
        int t2 = p + 2; if (t2 >= NP) t2 -= NP;
        const int j2 = jbase + t2 * 32;
        int b2 = bcur + 2; if (b2 >= 3) b2 -= 3;
        stage_v32c(v, &vlds[grp][b2][0], wg, lane, j2);
        const short8 ket = *(const short8*)(k + (size_t)(j2 + 2 * li    ) * D_DIM + 8 * g);
        const short8 kot = *(const short8*)(k + (size_t)(j2 + 2 * li + 1) * D_DIM + 8 * g);

        const f32x4 z = (f32x4){0.f, 0.f, 0.f, 0.f};
        short8 pa[2];
#pragma unroll
        for (int it = 0; it < 2; ++it) {
            f32x4 se = __builtin_amdgcn_mfma_f32_16x16x32_bf16(keC, qf[it], z, 0, 0, 0);
            f32x4 so = __builtin_amdgcn_mfma_f32_16x16x32_bf16(koC, qf[it], z, 0, 0, 0);
            float pe[4], po[4];
#pragma unroll
            for (int r = 0; r < 4; ++r) {
                pe[r] = exp2_fast(se[r]);   // P = 2^(s*log2e), static shift
                po[r] = exp2_fast(so[r]);
            }
            lsum[it] += ((pe[0] + po[0]) + (pe[1] + po[1]))
                      + ((pe[2] + po[2]) + (pe[3] + po[3]));
#pragma unroll
            for (int r = 0; r < 4; ++r) {
                pa[it][2 * r]     = (short)f2bf_fast(pe[r]);
                pa[it][2 * r + 1] = (short)f2bf_fast(po[r]);
            }
        }

        // O += P * V^T ; each V b128 feeds 2 MFMAs
        const short* vb = &vlds[grp][bcur][0];
        __builtin_amdgcn_s_setprio(1);
#pragma unroll
        for (int cf = 0; cf < 8; ++cf) {
            const short8 vf = *(const short8*)&vb[(cf * 16 + li) * 32 + roff];
            acc[0][cf] = __builtin_amdgcn_mfma_f32_16x16x32_bf16(pa[0], vf, acc[0][cf], 0, 0, 0);
            acc[1][cf] = __builtin_amdgcn_mfma_f32_16x16x32_bf16(pa[1], vf, acc[1][cf], 0, 0, 0);
        }
        __builtin_amdgcn_s_setprio(0);

        // counted wait: stage(t+1) landed; {K(t+1),stage(t+2),K(t+2)} in flight
        asm volatile("s_waitcnt vmcnt(8)" ::: "memory");
        __builtin_amdgcn_s_barrier();

        keC = keN; koC = koN; keN = ket; koN = kot;
        bcur = (bcur == 2) ? 0 : bcur + 1;
    }

    // ---- merge the 2 j-half partials: pure add (static-max => same scale) ----
#pragma unroll
    for (int it = 0; it < 2; ++it) {
        lsum[it] += __shfl_xor(lsum[it], 16);
        lsum[it] += __shfl_xor(lsum[it], 32);
        lscr[grp][wg][lane][it] = lsum[it];
    }

    f32x4* pv = (f32x4*)&vlds[0][0][0];   // reuse LDS as merge scratch
#pragma unroll
    for (int it = 0; it < 2; ++it) {
        __syncthreads();                  // full drain (also retires wrap stages)
        if (grp == 1) {
#pragma unroll
            for (int cf = 0; cf < 8; ++cf)
                pv[(wg * 8 + cf) * 64 + lane] = acc[it][cf];
        }
        __syncthreads();
        if (grp == 0) {
#pragma unroll
            for (int cf = 0; cf < 8; ++cf) {
                const f32x4 o4 = pv[(wg * 8 + cf) * 64 + lane];
                acc[it][cf][0] += o4[0]; acc[it][cf][1] += o4[1];
                acc[it][cf][2] += o4[2]; acc[it][cf][3] += o4[3];
            }
        }
    }

    if (grp == 0) {
#pragma unroll
        for (int it = 0; it < 2; ++it) {
            const float linv = 1.0f / (lscr[0][wg][lane][it] + lscr[1][wg][lane][it]);
            float lr[4];
#pragma unroll
            for (int r = 0; r < 4; ++r) lr[r] = __shfl(linv, 4 * g + r);
#pragma unroll
            for (int cf = 0; cf < 8; ++cf)
#pragma unroll
                for (int r = 0; r < 4; ++r)
                    o[(size_t)(i0 + it * 16 + 4 * g + r) * C_DIM + cf * 16 + li] =
                        f2bf(acc[it][cf][r] * lr[r]);
        }
    }
}

// ---------------------------------------------------------------------------
// Kernel 4: out[b][c][i] = x1 + x2 + O1[b][i][c] + O2[b][i][c]  (LDS transpose)
// ---------------------------------------------------------------------------
__global__ __launch_bounds__(256) void epilogue(
    const float* __restrict__ x1, const float* __restrict__ x2,
    const u16* __restrict__ O, float* __restrict__ out)
{
    __shared__ float tl[64][65];
    const int it = blockIdx.x, ct = blockIdx.y, b = blockIdx.z;
    const int tid = threadIdx.x;
    const int cl = tid & 63, r0 = tid >> 6;

    const u16* O1 = O + (size_t)(b)     * N_TOK * C_DIM;
    const u16* O2 = O + (size_t)(4 + b) * N_TOK * C_DIM;

#pragma unroll
    for (int rr = 0; rr < 16; ++rr) {
        const int il = r0 + rr * 4;
        const size_t off = (size_t)(it * 64 + il) * C_DIM + ct * 64 + cl;
        tl[il][cl] = bf2f(O1[off]) + bf2f(O2[off]);
    }
    __syncthreads();
#pragma unroll
    for (int rr = 0; rr < 16; ++rr) {
        const int c2 = r0 + rr * 4;
        const size_t idx = ((size_t)b * C_DIM + ct * 64 + c2) * N_TOK + it * 64 + cl;
        out[idx] = x1[idx] + x2[idx] + tl[cl][c2];
    }
}

// ---------------------------------------------------------------------------
extern "C" void kernel_launch(void* const* d_in, const int* in_sizes, int n_in,
                              void* d_out, int out_size, void* d_ws, size_t ws_size,
                              hipStream_t stream)
{
    const float* x1  = (const float*)d_in[0];
    const float* x2  = (const float*)d_in[1];
    const float* wq1 = (const float*)d_in[2];
    const float* bq1 = (const float*)d_in[3];
    const float* wk1 = (const float*)d_in[4];
    const float* bk1 = (const float*)d_in[5];
    const float* wv1 = (const float*)d_in[6];
    const float* bv1 = (const float*)d_in[7];
    const float* wq2 = (const float*)d_in[8];
    const float* bq2 = (const float*)d_in[9];
    const float* wk2 = (const float*)d_in[10];
    const float* bk2 = (const float*)d_in[11];
    const float* wv2 = (const float*)d_in[12];
    const float* bv2 = (const float*)d_in[13];
    float* out = (float*)d_out;

    // ws layout (bf16): Q[8][4096][32] | K[8][4096][32] | Vpacked[8][1M] | O[8][4096][256]
    u16* wsQ = (u16*)d_ws;
    u16* wsK = wsQ + (size_t)8 * N_TOK * D_DIM;
    u16* wsV = wsK + (size_t)8 * N_TOK * D_DIM;
    u16* wsO = wsV + (size_t)8 * C_DIM * N_TOK;

    qk_proj<<<dim3(64, 16), 256, 0, stream>>>(x1, x2, wq1, bq1, wk1, bk1,
                                              wq2, bq2, wk2, bk2, wsQ, wsK);
    v_proj<<<dim3(32, 2, 8), 256, 0, stream>>>(x2, wv1, bv1, wv2, bv2, wsV);
    attn_fwd<<<dim3(1024), 256, 0, stream>>>(wsQ, wsK, wsV, wsO);
    epilogue<<<dim3(64, 4, 4), 256, 0, stream>>>(x1, x2, wsO, out);
}

// Round 10
// 167.547 us; speedup vs baseline: 1.2864x; 1.2864x over previous
//
#include <hip/hip_runtime.h>

// Problem constants
#define N_TOK 4096   // H*W
#define C_DIM 256
#define D_DIM 32

typedef float f32x4 __attribute__((ext_vector_type(4)));
typedef short short8 __attribute__((ext_vector_type(8)));
typedef unsigned short u16;

__device__ __forceinline__ u16 f2bf(float f) {
    unsigned int u = __builtin_bit_cast(unsigned int, f);
    u += 0x7fffu + ((u >> 16) & 1u);   // round-to-nearest-even
    return (u16)(u >> 16);
}
__device__ __forceinline__ u16 f2bf_fast(float f) {   // round-half-up (f >= 0)
    return (u16)((__builtin_bit_cast(unsigned int, f) + 0x8000u) >> 16);
}
__device__ __forceinline__ float bf2f(u16 h) {
    unsigned int u = ((unsigned int)h) << 16;
    return __builtin_bit_cast(float, u);
}
__device__ __forceinline__ float exp2_fast(float x) {  // 2^x, compiler-managed
#if __has_builtin(__builtin_amdgcn_exp2f)
    return __builtin_amdgcn_exp2f(x);
#else
    return exp2f(x);
#endif
}

// Packed V layout (bf16 shorts), per slice (1M shorts = 2MB):
//   addr = jblk*8192 + c*32 + pos*8 + (j&7),  jblk = j>>5,
//   pos  = ((j>>3)&3) ^ ((c>>1)&3)            (chunk XOR swizzle baked in)
// A jblk-tile is contiguous 16KB; its c-half [128,256) is a contiguous 8KB.

// ---------------------------------------------------------------------------
// Kernel 1: q/k projection.  q = (wq*x1 + bq)*log2e, k = wk*x2 + bk
// Output layout: Q[slice][i][d], K[slice][j][d]  (d contiguous, bf16)
// ---------------------------------------------------------------------------
__global__ __launch_bounds__(256) void qk_proj(
    const float* __restrict__ x1, const float* __restrict__ x2,
    const float* __restrict__ wq1, const float* __restrict__ bq1,
    const float* __restrict__ wk1, const float* __restrict__ bk1,
    const float* __restrict__ wq2, const float* __restrict__ bq2,
    const float* __restrict__ wk2, const float* __restrict__ bk2,
    u16* __restrict__ wsQ, u16* __restrict__ wsK)
{
    __shared__ float w_lds[32 * 256];
    const int ib = blockIdx.x;
    const int comb = blockIdx.y;
    const int b = comb & 3;
    const int branch = (comb >> 2) & 1;
    const int qk = comb >> 3;

    const float* x = qk ? x2 : x1;           // q from x1; k from x2
    const float* w; const float* bias; u16* dst;
    if (qk == 0) { w = branch ? wq2 : wq1; bias = branch ? bq2 : bq1; dst = wsQ; }
    else         { w = branch ? wk2 : wk1; bias = branch ? bk2 : bk1; dst = wsK; }
    const int slice = branch * 4 + b;
    dst += (size_t)slice * N_TOK * D_DIM;
    const float osc = (qk == 0) ? 1.44269504088896341f : 1.0f;

    const int tid = threadIdx.x;
    for (int t = tid; t < 32 * 256; t += 256) w_lds[t] = w[t];
    __syncthreads();

    const int il = tid & 63;
    const int db = tid >> 6;                 // 0..3 -> d = db*8 + mm
    const float* xc = x + (size_t)b * C_DIM * N_TOK + ib * 64 + il;

    float acc[8] = {0.f,0.f,0.f,0.f,0.f,0.f,0.f,0.f};
    for (int c4 = 0; c4 < 256; c4 += 4) {
        const float xv0 = xc[(size_t)(c4 + 0) * N_TOK];
        const float xv1 = xc[(size_t)(c4 + 1) * N_TOK];
        const float xv2 = xc[(size_t)(c4 + 2) * N_TOK];
        const float xv3 = xc[(size_t)(c4 + 3) * N_TOK];
#pragma unroll
        for (int mm = 0; mm < 8; ++mm) {
            const float4 wv = *(const float4*)&w_lds[(db * 8 + mm) * 256 + c4];
            acc[mm] += xv0 * wv.x + xv1 * wv.y + xv2 * wv.z + xv3 * wv.w;
        }
    }
    short8 pack;
#pragma unroll
    for (int mm = 0; mm < 8; ++mm)
        pack[mm] = (short)f2bf((acc[mm] + bias[db * 8 + mm]) * osc);
    *(short8*)(dst + (size_t)(ib * 64 + il) * D_DIM + db * 8) = pack;
}

// ---------------------------------------------------------------------------
// Kernel 2: v projection via MFMA, writing PACKED V tiles.
// block 256 (4 waves, 2x2 wave grid), tile 128c x 128j, K=256 in 8 steps.
// grid (32 jt, 2 ct, 8 slices)
// ---------------------------------------------------------------------------
__device__ __forceinline__ void stage_xt(u16* xtb, const float* xb, int ks,
                                         int wave, int lane)
{
    // XT[j][k] (32 k per buf, 64B rows), chunk kc stored at pos kc ^ ((j>>1)&3)
    const int j  = (wave & 1) * 64 + lane;
    const int cb = (wave >> 1) * 16;       // k (cin) base, 16 per thread
    const float* xp = xb + (size_t)(ks * 32 + cb) * N_TOK + j;
    u16 vals[16];
#pragma unroll
    for (int qq = 0; qq < 16; ++qq) vals[qq] = f2bf(xp[(size_t)qq * N_TOK]);
    const int swz = (j >> 1) & 3;
    u16* row = xtb + j * 32;
    const int c0 = cb >> 3;
    *(short8*)&row[((c0    ) ^ swz) * 8] = *(const short8*)&vals[0];
    *(short8*)&row[((c0 + 1) ^ swz) * 8] = *(const short8*)&vals[8];
}

__global__ __launch_bounds__(256, 2) void v_proj(
    const float* __restrict__ x2,
    const float* __restrict__ wv1, const float* __restrict__ bv1,
    const float* __restrict__ wv2, const float* __restrict__ bv2,
    u16* __restrict__ wsV)
{
    __shared__ __align__(16) u16 wl[128 * 256];     // [c][k] swizzled, 64 KB
    __shared__ __align__(16) u16 xt[2][128 * 32];   // [j][k] swizzled, 16 KB

    const int jt = blockIdx.x, ct = blockIdx.y, s = blockIdx.z;
    const int branch = s >> 2, b = s & 3;
    const float* w    = branch ? wv2 : wv1;
    const float* bias = branch ? bv2 : bv1;
    u16* dst = wsV + (size_t)s * C_DIM * N_TOK;     // packed slice base
    const float* xb = x2 + (size_t)b * C_DIM * N_TOK + jt * 128;

    const int tid = threadIdx.x;
    const int wave = tid >> 6, lane = tid & 63;
    const int wr = wave >> 1, wc = wave & 1;
    const int g = lane >> 4, li = lane & 15;

    // ---- stage W[128c][256k] -> bf16 LDS, chunk kc at pos kc ^ (c&7)
    {
        const int c = tid >> 1;
        const int kh = (tid & 1) * 128;
        const float* wrow = w + (size_t)(ct * 128 + c) * C_DIM + kh;
        u16* lrow = wl + c * 256;
#pragma unroll
        for (int kk = 0; kk < 128; kk += 8) {
            const float4 a0 = *(const float4*)&wrow[kk];
            const float4 a1 = *(const float4*)&wrow[kk + 4];
            u16 tmp[8] = {f2bf(a0.x), f2bf(a0.y), f2bf(a0.z), f2bf(a0.w),
                          f2bf(a1.x), f2bf(a1.y), f2bf(a1.z), f2bf(a1.w)};
            const int kc = (kh + kk) >> 3;
            *(short8*)&lrow[(kc ^ (c & 7)) * 8] = *(const short8*)tmp;
        }
    }
    stage_xt(&xt[0][0], xb, 0, wave, lane);
    __syncthreads();

    f32x4 acc[4][4];
#pragma unroll
    for (int mf = 0; mf < 4; ++mf)
#pragma unroll
        for (int nf = 0; nf < 4; ++nf) acc[mf][nf] = (f32x4){0.f, 0.f, 0.f, 0.f};

    int buf = 0;
    for (int ks = 0; ks < 8; ++ks) {
        if (ks < 7) stage_xt(&xt[buf ^ 1][0], xb, ks + 1, wave, lane);

        short8 af[4], bf[4];
#pragma unroll
        for (int mf = 0; mf < 4; ++mf) {
            const int c = wr * 64 + mf * 16 + li;
            af[mf] = *(const short8*)&wl[c * 256 + (((ks * 4 + g) ^ (li & 7)) * 8)];
        }
#pragma unroll
        for (int nf = 0; nf < 4; ++nf) {
            const int j = wc * 64 + nf * 16 + li;
            bf[nf] = *(const short8*)&xt[buf][j * 32 + ((g ^ ((j >> 1) & 3)) * 8)];
        }
        __builtin_amdgcn_s_setprio(1);
#pragma unroll
        for (int mf = 0; mf < 4; ++mf)
#pragma unroll
            for (int nf = 0; nf < 4; ++nf)
                acc[mf][nf] = __builtin_amdgcn_mfma_f32_16x16x32_bf16(
                    af[mf], bf[nf], acc[mf][nf], 0, 0, 0);
        __builtin_amdgcn_s_setprio(0);
        __syncthreads();
        buf ^= 1;
    }

    // ---- epilogue: write packed-swizzled tiles
#pragma unroll
    for (int mf = 0; mf < 4; ++mf) {
#pragma unroll
        for (int r = 0; r < 4; ++r) {
            const int c = ct * 128 + wr * 64 + mf * 16 + 4 * g + r;
            const float bv = bias[c];
            const int cswz = (c >> 1) & 3;
            u16* crow = dst + c * 32;
#pragma unroll
            for (int nf = 0; nf < 4; ++nf) {
                const int j = jt * 128 + wc * 64 + nf * 16 + li;
                const int pos = ((j >> 3) & 3) ^ cswz;
                crow[(size_t)(j >> 5) * 8192 + pos * 8 + (j & 7)] =
                    f2bf(acc[mf][nf][r] + bv);
            }
        }
    }
}

// ---------------------------------------------------------------------------
// Kernel 3: flash attention, static-max exp2 softmax, c-split.
// (round-8 structure + K register prefetch 1 period ahead)
// block 256 = 4 waves = 2 j-halves (grp) x 2 i-halves (wg); R=2 (32 i/wave);
// each block owns a 128-c half (ct).  acc[2][8] = 64 VGPRs, no spill.
// K(t+1) issued at top of period t, consumed next period (drain at the
// period-end __syncthreads guarantees it landed -> K latency off the path).
// grid 1024: n = slice + 8*(ib + 64*ct); slice = n%8 -> XCD affinity.
// V stage = linear contiguous 8KB (c-half of packed tile); PV read
// pos = g ^ ((li>>1)&3): measured 0 bank conflicts (rounds 6-8).
// ---------------------------------------------------------------------------
__global__ __launch_bounds__(256, 4) void attn_fwd(
    const u16* __restrict__ Q, const u16* __restrict__ K,
    const u16* __restrict__ V, u16* __restrict__ O)
{
    __shared__ __align__(16) short vlds[2][2][128 * 32];  // [grp][buf] 32 KB
    __shared__ float lscr[2][2][64][2];                   // [grp][wg][lane][it]

    const int n  = blockIdx.x;
    const int s  = n & 7;              // slice -> XCD (n%8)
    const int ib = (n >> 3) & 63;      // i-block of 64 rows
    const int ct = n >> 9;             // c-half
    const u16* q = Q + (size_t)s * N_TOK * D_DIM;
    const u16* k = K + (size_t)s * N_TOK * D_DIM;
    const u16* v = V + (size_t)s * C_DIM * N_TOK + ct * 4096;  // c-half in tile
    u16*       o = O + (size_t)s * N_TOK * C_DIM + ct * 128;

    const int tid  = threadIdx.x;
    const int wave = tid >> 6;
    const int lane = tid & 63;
    const int grp  = wave >> 1;        // j-half
    const int wg   = wave & 1;
    const int g    = lane >> 4;
    const int li   = lane & 15;
    const int i0   = ib * 64 + wg * 32;
    const int jbase = grp * (N_TOK / 2);
    const int NP = N_TOK / 2 / 32;     // 64 periods of 32 j

    short8 qf[2];
    qf[0] = *(const short8*)(q + (size_t)(i0 + li) * D_DIM + 8 * g);
    qf[1] = *(const short8*)(q + (size_t)(i0 + 16 + li) * D_DIM + 8 * g);

    f32x4 acc[2][8];
#pragma unroll
    for (int it = 0; it < 2; ++it)
#pragma unroll
        for (int cf = 0; cf < 8; ++cf) acc[it][cf] = (f32x4){0.f, 0.f, 0.f, 0.f};
    float lsum[2] = {0.f, 0.f};

    const int roff = (g ^ ((li >> 1) & 3)) << 3;   // swizzled chunk offset

    // prologue: V tile 0 + K(0) fragments
    {
        const u16* tile = v + (size_t)(jbase >> 5) * 8192;
#pragma unroll
        for (int ii = 0; ii < 4; ++ii) {
            const int off = (wg * 4 + ii) * 512;
            __builtin_amdgcn_global_load_lds(
                (const __attribute__((address_space(1))) void*)(tile + off + lane * 8),
                (__attribute__((address_space(3))) void*)(&vlds[grp][0][0] + off),
                16, 0, 0);
        }
    }
    short8 keC = *(const short8*)(k + (size_t)(jbase + 2 * li    ) * D_DIM + 8 * g);
    short8 koC = *(const short8*)(k + (size_t)(jbase + 2 * li + 1) * D_DIM + 8 * g);
    __syncthreads();

    int buf = 0;
    for (int p = 0; p < NP; ++p) {
        short8 keN, koN;
        if (p < NP - 1) {
            // stage next V tile (async) + prefetch next K into regs
            const int jn = jbase + (p + 1) * 32;
            const u16* tile = v + (size_t)(jn >> 5) * 8192;
            short* dst = &vlds[grp][buf ^ 1][0];
#pragma unroll
            for (int ii = 0; ii < 4; ++ii) {
                const int off = (wg * 4 + ii) * 512;
                __builtin_amdgcn_global_load_lds(
                    (const __attribute__((address_space(1))) void*)(tile + off + lane * 8),
                    (__attribute__((address_space(3))) void*)(dst + off),
                    16, 0, 0);
            }
            keN = *(const short8*)(k + (size_t)(jn + 2 * li    ) * D_DIM + 8 * g);
            koN = *(const short8*)(k + (size_t)(jn + 2 * li + 1) * D_DIM + 8 * g);
        }

        const f32x4 z = (f32x4){0.f, 0.f, 0.f, 0.f};
        short8 pa[2];
#pragma unroll
        for (int it = 0; it < 2; ++it) {
            f32x4 se = __builtin_amdgcn_mfma_f32_16x16x32_bf16(keC, qf[it], z, 0, 0, 0);
            f32x4 so = __builtin_amdgcn_mfma_f32_16x16x32_bf16(koC, qf[it], z, 0, 0, 0);
            float pe[4], po[4];
#pragma unroll
            for (int r = 0; r < 4; ++r) {
                pe[r] = exp2_fast(se[r]);   // P = 2^(s*log2e), static shift
                po[r] = exp2_fast(so[r]);
            }
            lsum[it] += ((pe[0] + po[0]) + (pe[1] + po[1]))
                      + ((pe[2] + po[2]) + (pe[3] + po[3]));
#pragma unroll
            for (int r = 0; r < 4; ++r) {
                pa[it][2 * r]     = (short)f2bf_fast(pe[r]);
                pa[it][2 * r + 1] = (short)f2bf_fast(po[r]);
            }
        }

        // O += P * V^T ; each V b128 feeds 2 MFMAs
        const short* vb = &vlds[grp][buf][0];
        __builtin_amdgcn_s_setprio(1);
#pragma unroll
        for (int cf = 0; cf < 8; ++cf) {
            const short8 vf = *(const short8*)&vb[(cf * 16 + li) * 32 + roff];
            acc[0][cf] = __builtin_amdgcn_mfma_f32_16x16x32_bf16(pa[0], vf, acc[0][cf], 0, 0, 0);
            acc[1][cf] = __builtin_amdgcn_mfma_f32_16x16x32_bf16(pa[1], vf, acc[1][cf], 0, 0, 0);
        }
        __builtin_amdgcn_s_setprio(0);
        __syncthreads();
        buf ^= 1;
        if (p < NP - 1) { keC = keN; koC = koN; }
    }

    // ---- merge the 2 j-half partials: pure add (static-max => same scale) ----
#pragma unroll
    for (int it = 0; it < 2; ++it) {
        lsum[it] += __shfl_xor(lsum[it], 16);
        lsum[it] += __shfl_xor(lsum[it], 32);
        lscr[grp][wg][lane][it] = lsum[it];
    }

    f32x4* pv = (f32x4*)&vlds[0][0][0];   // reuse 32 KB as merge scratch
#pragma unroll
    for (int it = 0; it < 2; ++it) {
        __syncthreads();
        if (grp == 1) {
#pragma unroll
            for (int cf = 0; cf < 8; ++cf)
                pv[(wg * 8 + cf) * 64 + lane] = acc[it][cf];
        }
        __syncthreads();
        if (grp == 0) {
#pragma unroll
            for (int cf = 0; cf < 8; ++cf) {
                const f32x4 o4 = pv[(wg * 8 + cf) * 64 + lane];
                acc[it][cf][0] += o4[0]; acc[it][cf][1] += o4[1];
                acc[it][cf][2] += o4[2]; acc[it][cf][3] += o4[3];
            }
        }
    }

    if (grp == 0) {
#pragma unroll
        for (int it = 0; it < 2; ++it) {
            const float linv = 1.0f / (lscr[0][wg][lane][it] + lscr[1][wg][lane][it]);
            float lr[4];
#pragma unroll
            for (int r = 0; r < 4; ++r) lr[r] = __shfl(linv, 4 * g + r);
#pragma unroll
            for (int cf = 0; cf < 8; ++cf)
#pragma unroll
                for (int r = 0; r < 4; ++r)
                    o[(size_t)(i0 + it * 16 + 4 * g + r) * C_DIM + cf * 16 + li] =
                        f2bf(acc[it][cf][r] * lr[r]);
        }
    }
}

// ---------------------------------------------------------------------------
// Kernel 4: out[b][c][i] = x1 + x2 + O1[b][i][c] + O2[b][i][c]  (LDS transpose)
// ---------------------------------------------------------------------------
__global__ __launch_bounds__(256) void epilogue(
    const float* __restrict__ x1, const float* __restrict__ x2,
    const u16* __restrict__ O, float* __restrict__ out)
{
    __shared__ float tl[64][65];
    const int it = blockIdx.x, ct = blockIdx.y, b = blockIdx.z;
    const int tid = threadIdx.x;
    const int cl = tid & 63, r0 = tid >> 6;

    const u16* O1 = O + (size_t)(b)     * N_TOK * C_DIM;
    const u16* O2 = O + (size_t)(4 + b) * N_TOK * C_DIM;

#pragma unroll
    for (int rr = 0; rr < 16; ++rr) {
        const int il = r0 + rr * 4;
        const size_t off = (size_t)(it * 64 + il) * C_DIM + ct * 64 + cl;
        tl[il][cl] = bf2f(O1[off]) + bf2f(O2[off]);
    }
    __syncthreads();
#pragma unroll
    for (int rr = 0; rr < 16; ++rr) {
        const int c2 = r0 + rr * 4;
        const size_t idx = ((size_t)b * C_DIM + ct * 64 + c2) * N_TOK + it * 64 + cl;
        out[idx] = x1[idx] + x2[idx] + tl[cl][c2];
    }
}

// ---------------------------------------------------------------------------
extern "C" void kernel_launch(void* const* d_in, const int* in_sizes, int n_in,
                              void* d_out, int out_size, void* d_ws, size_t ws_size,
                              hipStream_t stream)
{
    const float* x1  = (const float*)d_in[0];
    const float* x2  = (const float*)d_in[1];
    const float* wq1 = (const float*)d_in[2];
    const float* bq1 = (const float*)d_in[3];
    const float* wk1 = (const float*)d_in[4];
    const float* bk1 = (const float*)d_in[5];
    const float* wv1 = (const float*)d_in[6];
    const float* bv1 = (const float*)d_in[7];
    const float* wq2 = (const float*)d_in[8];
    const float* bq2 = (const float*)d_in[9];
    const float* wk2 = (const float*)d_in[10];
    const float* bk2 = (const float*)d_in[11];
    const float* wv2 = (const float*)d_in[12];
    const float* bv2 = (const float*)d_in[13];
    float* out = (float*)d_out;

    // ws layout (bf16): Q[8][4096][32] | K[8][4096][32] | Vpacked[8][1M] | O[8][4096][256]
    u16* wsQ = (u16*)d_ws;
    u16* wsK = wsQ + (size_t)8 * N_TOK * D_DIM;
    u16* wsV = wsK + (size_t)8 * N_TOK * D_DIM;
    u16* wsO = wsV + (size_t)8 * C_DIM * N_TOK;

    qk_proj<<<dim3(64, 16), 256, 0, stream>>>(x1, x2, wq1, bq1, wk1, bk1,
                                              wq2, bq2, wk2, bk2, wsQ, wsK);
    v_proj<<<dim3(32, 2, 8), 256, 0, stream>>>(x2, wv1, bv1, wv2, bv2, wsV);
    attn_fwd<<<dim3(1024), 256, 0, stream>>>(wsQ, wsK, wsV, wsO);
    epilogue<<<dim3(64, 4, 4), 256, 0, stream>>>(x1, x2, wsO, out);
}

// Round 12
// 139.250 us; speedup vs baseline: 1.5478x; 1.2032x over previous
//
#include <hip/hip_runtime.h>
#include <hip/hip_fp8.h>

// Problem constants
#define N_TOK 4096   // H*W
#define C_DIM 256
#define D_DIM 32

typedef float f32x4 __attribute__((ext_vector_type(4)));
typedef short short8 __attribute__((ext_vector_type(8)));
typedef unsigned short u16;
typedef unsigned char u8;
typedef long long i64;

__device__ __forceinline__ u16 f2bf(float f) {
    unsigned int u = __builtin_bit_cast(unsigned int, f);
    u += 0x7fffu + ((u >> 16) & 1u);   // round-to-nearest-even
    return (u16)(u >> 16);
}
__device__ __forceinline__ float bf2f(u16 h) {
    unsigned int u = ((unsigned int)h) << 16;
    return __builtin_bit_cast(float, u);
}
__device__ __forceinline__ float exp2_fast(float x) {  // 2^x, compiler-managed
#if __has_builtin(__builtin_amdgcn_exp2f)
    return __builtin_amdgcn_exp2f(x);
#else
    return exp2f(x);
#endif
}
// pack 2 f32 -> 2 OCP e4m3 bytes into half of a dword (HI is compile-time)
template<bool HI>
__device__ __forceinline__ int pk_fp8(float a, float b, int old) {
#if __has_builtin(__builtin_amdgcn_cvt_pk_fp8_f32)
    return __builtin_amdgcn_cvt_pk_fp8_f32(a, b, old, HI);
#else
    __hip_fp8_e4m3 fa(a), fb(b);
    int v = (int)fa.__x | ((int)fb.__x << 8);
    return HI ? ((old & 0xffff) | (v << 16)) : ((old & ~0xffff) | (v & 0xffff));
#endif
}
__device__ __forceinline__ u8 f2fp8(float f) {
    return (u8)(pk_fp8<false>(f, f, 0) & 0xff);
}

// Packed V layout (fp8 e4m3 bytes), per slice (1 MB):
//   byte = jblk*8192 + p*2048 + c*8 + (j&7),  jblk = j>>5,  p = (j>>3)&3
// p outermost => PV b64 reads hit each bank exactly 4x (structural minimum);
// a (jblk, p, c-half) chunk is a contiguous 1 KB -> linear stage copy.

// ---------------------------------------------------------------------------
// Kernel 1: q/k projection.  q = (wq*x1 + bq)*log2e, k = wk*x2 + bk
// Output layout: Q[slice][i][d], K[slice][j][d]  (d contiguous, bf16)
// ---------------------------------------------------------------------------
__global__ __launch_bounds__(256) void qk_proj(
    const float* __restrict__ x1, const float* __restrict__ x2,
    const float* __restrict__ wq1, const float* __restrict__ bq1,
    const float* __restrict__ wk1, const float* __restrict__ bk1,
    const float* __restrict__ wq2, const float* __restrict__ bq2,
    const float* __restrict__ wk2, const float* __restrict__ bk2,
    u16* __restrict__ wsQ, u16* __restrict__ wsK)
{
    __shared__ float w_lds[32 * 256];
    const int ib = blockIdx.x;
    const int comb = blockIdx.y;
    const int b = comb & 3;
    const int branch = (comb >> 2) & 1;
    const int qk = comb >> 3;

    const float* x = qk ? x2 : x1;           // q from x1; k from x2
    const float* w; const float* bias; u16* dst;
    if (qk == 0) { w = branch ? wq2 : wq1; bias = branch ? bq2 : bq1; dst = wsQ; }
    else         { w = branch ? wk2 : wk1; bias = branch ? bk2 : bk1; dst = wsK; }
    const int slice = branch * 4 + b;
    dst += (size_t)slice * N_TOK * D_DIM;
    const float osc = (qk == 0) ? 1.44269504088896341f : 1.0f;

    const int tid = threadIdx.x;
    for (int t = tid; t < 32 * 256; t += 256) w_lds[t] = w[t];
    __syncthreads();

    const int il = tid & 63;
    const int db = tid >> 6;                 // 0..3 -> d = db*8 + mm
    const float* xc = x + (size_t)b * C_DIM * N_TOK + ib * 64 + il;

    float acc[8] = {0.f,0.f,0.f,0.f,0.f,0.f,0.f,0.f};
    for (int c4 = 0; c4 < 256; c4 += 4) {
        const float xv0 = xc[(size_t)(c4 + 0) * N_TOK];
        const float xv1 = xc[(size_t)(c4 + 1) * N_TOK];
        const float xv2 = xc[(size_t)(c4 + 2) * N_TOK];
        const float xv3 = xc[(size_t)(c4 + 3) * N_TOK];
#pragma unroll
        for (int mm = 0; mm < 8; ++mm) {
            const float4 wv = *(const float4*)&w_lds[(db * 8 + mm) * 256 + c4];
            acc[mm] += xv0 * wv.x + xv1 * wv.y + xv2 * wv.z + xv3 * wv.w;
        }
    }
    short8 pack;
#pragma unroll
    for (int mm = 0; mm < 8; ++mm)
        pack[mm] = (short)f2bf((acc[mm] + bias[db * 8 + mm]) * osc);
    *(short8*)(dst + (size_t)(ib * 64 + il) * D_DIM + db * 8) = pack;
}

// ---------------------------------------------------------------------------
// Kernel 2: v projection via MFMA, writing PACKED fp8 V.
// block 256 (4 waves, 2x2 wave grid), tile 128c x 128j, K=256 in 8 steps.
// grid (32 jt, 2 ct, 8 slices)
// ---------------------------------------------------------------------------
__device__ __forceinline__ void stage_xt(u16* xtb, const float* xb, int ks,
                                         int wave, int lane)
{
    // XT[j][k] (32 k per buf, 64B rows), chunk kc stored at pos kc ^ ((j>>1)&3)
    const int j  = (wave & 1) * 64 + lane;
    const int cb = (wave >> 1) * 16;       // k (cin) base, 16 per thread
    const float* xp = xb + (size_t)(ks * 32 + cb) * N_TOK + j;
    u16 vals[16];
#pragma unroll
    for (int qq = 0; qq < 16; ++qq) vals[qq] = f2bf(xp[(size_t)qq * N_TOK]);
    const int swz = (j >> 1) & 3;
    u16* row = xtb + j * 32;
    const int c0 = cb >> 3;
    *(short8*)&row[((c0    ) ^ swz) * 8] = *(const short8*)&vals[0];
    *(short8*)&row[((c0 + 1) ^ swz) * 8] = *(const short8*)&vals[8];
}

__global__ __launch_bounds__(256, 2) void v_proj(
    const float* __restrict__ x2,
    const float* __restrict__ wv1, const float* __restrict__ bv1,
    const float* __restrict__ wv2, const float* __restrict__ bv2,
    u8* __restrict__ wsV)
{
    __shared__ __align__(16) u16 wl[128 * 256];     // [c][k] swizzled, 64 KB
    __shared__ __align__(16) u16 xt[2][128 * 32];   // [j][k] swizzled, 16 KB

    const int jt = blockIdx.x, ct = blockIdx.y, s = blockIdx.z;
    const int branch = s >> 2, b = s & 3;
    const float* w    = branch ? wv2 : wv1;
    const float* bias = branch ? bv2 : bv1;
    u8* dstB = wsV + (size_t)s * N_TOK * C_DIM;     // packed fp8 slice (1 MB)
    const float* xb = x2 + (size_t)b * C_DIM * N_TOK + jt * 128;

    const int tid = threadIdx.x;
    const int wave = tid >> 6, lane = tid & 63;
    const int wr = wave >> 1, wc = wave & 1;
    const int g = lane >> 4, li = lane & 15;

    // ---- stage W[128c][256k] -> bf16 LDS, chunk kc at pos kc ^ (c&7)
    {
        const int c = tid >> 1;
        const int kh = (tid & 1) * 128;
        const float* wrow = w + (size_t)(ct * 128 + c) * C_DIM + kh;
        u16* lrow = wl + c * 256;
#pragma unroll
        for (int kk = 0; kk < 128; kk += 8) {
            const float4 a0 = *(const float4*)&wrow[kk];
            const float4 a1 = *(const float4*)&wrow[kk + 4];
            u16 tmp[8] = {f2bf(a0.x), f2bf(a0.y), f2bf(a0.z), f2bf(a0.w),
                          f2bf(a1.x), f2bf(a1.y), f2bf(a1.z), f2bf(a1.w)};
            const int kc = (kh + kk) >> 3;
            *(short8*)&lrow[(kc ^ (c & 7)) * 8] = *(const short8*)tmp;
        }
    }
    stage_xt(&xt[0][0], xb, 0, wave, lane);
    __syncthreads();

    f32x4 acc[4][4];
#pragma unroll
    for (int mf = 0; mf < 4; ++mf)
#pragma unroll
        for (int nf = 0; nf < 4; ++nf) acc[mf][nf] = (f32x4){0.f, 0.f, 0.f, 0.f};

    int buf = 0;
    for (int ks = 0; ks < 8; ++ks) {
        if (ks < 7) stage_xt(&xt[buf ^ 1][0], xb, ks + 1, wave, lane);

        short8 af[4], bf[4];
#pragma unroll
        for (int mf = 0; mf < 4; ++mf) {
            const int c = wr * 64 + mf * 16 + li;
            af[mf] = *(const short8*)&wl[c * 256 + (((ks * 4 + g) ^ (li & 7)) * 8)];
        }
#pragma unroll
        for (int nf = 0; nf < 4; ++nf) {
            const int j = wc * 64 + nf * 16 + li;
            bf[nf] = *(const short8*)&xt[buf][j * 32 + ((g ^ ((j >> 1) & 3)) * 8)];
        }
        __builtin_amdgcn_s_setprio(1);
#pragma unroll
        for (int mf = 0; mf < 4; ++mf)
#pragma unroll
            for (int nf = 0; nf < 4; ++nf)
                acc[mf][nf] = __builtin_amdgcn_mfma_f32_16x16x32_bf16(
                    af[mf], bf[nf], acc[mf][nf], 0, 0, 0);
        __builtin_amdgcn_s_setprio(0);
        __syncthreads();
        buf ^= 1;
    }

    // ---- epilogue: write packed fp8 V
#pragma unroll
    for (int mf = 0; mf < 4; ++mf) {
#pragma unroll
        for (int r = 0; r < 4; ++r) {
            const int c = ct * 128 + wr * 64 + mf * 16 + 4 * g + r;
            const float bv = bias[c];
#pragma unroll
            for (int nf = 0; nf < 4; ++nf) {
                const int j = jt * 128 + wc * 64 + nf * 16 + li;
                dstB[(size_t)(j >> 5) * 8192 + ((j >> 3) & 3) * 2048
                     + c * 8 + (j & 7)] = f2fp8(acc[mf][nf][r] + bv);
            }
        }
    }
}

// ---------------------------------------------------------------------------
// Kernel 3: flash attention, static-max exp2 softmax, c-split, fp8 PV.
// block 256 = 4 waves = 2 j-halves (grp) x 2 i-halves (wg); R=2 (32 i/wave);
// each block owns a 128-c half (ct).  acc[2][8] = 64 VGPRs, no spill.
// V: fp8 packed [jblk][p][c][8B]; stage = 2 linear 1KB copies per wave;
// PV = mfma_f32_16x16x32_fp8_fp8, B operand one b64/lane (4 dwords/bank min).
// P -> fp8 via v_cvt_pk_fp8_f32 (4 insts/tile, replaces ~40 VALU bf16 pack).
// grid 1024: n = slice + 8*(ib + 64*ct); slice = n%8 -> XCD affinity.
// ---------------------------------------------------------------------------
__global__ __launch_bounds__(256, 4) void attn_fwd(
    const u16* __restrict__ Q, const u16* __restrict__ K,
    const u8* __restrict__ V, u16* __restrict__ O)
{
    __shared__ __align__(16) u8 vlds[2][2][4096];   // [grp][buf] 16 KB total
    __shared__ float lscr[2][2][64][2];             // [grp][wg][lane][it]

    const int n  = blockIdx.x;
    const int s  = n & 7;              // slice -> XCD (n%8)
    const int ib = (n >> 3) & 63;      // i-block of 64 rows
    const int ct = n >> 9;             // c-half
    const u16* q = Q + (size_t)s * N_TOK * D_DIM;
    const u16* k = K + (size_t)s * N_TOK * D_DIM;
    const u8*  v = V + (size_t)s * N_TOK * C_DIM + ct * 1024;  // c-half in p-chunks
    u16*       o = O + (size_t)s * N_TOK * C_DIM + ct * 128;

    const int tid  = threadIdx.x;
    const int wave = tid >> 6;
    const int lane = tid & 63;
    const int grp  = wave >> 1;        // j-half
    const int wg   = wave & 1;
    const int g    = lane >> 4;
    const int li   = lane & 15;
    const int i0   = ib * 64 + wg * 32;
    const int jbase = grp * (N_TOK / 2);
    const int NP = N_TOK / 2 / 32;     // 64 periods of 32 j

    short8 qf[2];
    qf[0] = *(const short8*)(q + (size_t)(i0 + li) * D_DIM + 8 * g);
    qf[1] = *(const short8*)(q + (size_t)(i0 + 16 + li) * D_DIM + 8 * g);

    f32x4 acc[2][8];
#pragma unroll
    for (int it = 0; it < 2; ++it)
#pragma unroll
        for (int cf = 0; cf < 8; ++cf) acc[it][cf] = (f32x4){0.f, 0.f, 0.f, 0.f};
    float lsum[2] = {0.f, 0.f};

    // prologue: V tile 0 (2 x 1KB linear chunks per wave)
    {
        const u8* tile = v + (size_t)(jbase >> 5) * 8192;
#pragma unroll
        for (int ii = 0; ii < 2; ++ii) {
            const int p = wg * 2 + ii;
            __builtin_amdgcn_global_load_lds(
                (const __attribute__((address_space(1))) void*)(tile + p * 2048 + lane * 16),
                (__attribute__((address_space(3))) void*)(&vlds[grp][0][0] + p * 1024),
                16, 0, 0);
        }
    }
    __syncthreads();

    int buf = 0;
    for (int p = 0; p < NP; ++p) {
        if (p < NP - 1) {               // stage next V tile (async)
            const u8* tile = v + (size_t)((jbase + (p + 1) * 32) >> 5) * 8192;
            u8* dst = &vlds[grp][buf ^ 1][0];
#pragma unroll
            for (int ii = 0; ii < 2; ++ii) {
                const int pc = wg * 2 + ii;
                __builtin_amdgcn_global_load_lds(
                    (const __attribute__((address_space(1))) void*)(tile + pc * 2048 + lane * 16),
                    (__attribute__((address_space(3))) void*)(dst + pc * 1024),
                    16, 0, 0);
            }
        }

        // K fragments for this period (L2-resident; TLP hides latency)
        const int j0 = jbase + p * 32;
        const short8 ke = *(const short8*)(k + (size_t)(j0 + 2 * li    ) * D_DIM + 8 * g);
        const short8 ko = *(const short8*)(k + (size_t)(j0 + 2 * li + 1) * D_DIM + 8 * g);

        const f32x4 z = (f32x4){0.f, 0.f, 0.f, 0.f};
        i64 paL[2];
#pragma unroll
        for (int it = 0; it < 2; ++it) {
            f32x4 se = __builtin_amdgcn_mfma_f32_16x16x32_bf16(ke, qf[it], z, 0, 0, 0);
            f32x4 so = __builtin_amdgcn_mfma_f32_16x16x32_bf16(ko, qf[it], z, 0, 0, 0);
            float pe[4], po[4];
#pragma unroll
            for (int r = 0; r < 4; ++r) {
                pe[r] = exp2_fast(se[r]);   // P = 2^(s*log2e), static shift
                po[r] = exp2_fast(so[r]);
            }
            lsum[it] += ((pe[0] + po[0]) + (pe[1] + po[1]))
                      + ((pe[2] + po[2]) + (pe[3] + po[3]));
            // pack P -> 8 fp8 bytes: byte e = j (8g+e); e=2r even (pe), 2r+1 odd (po)
            int w0 = pk_fp8<false>(pe[0], po[0], 0);
            w0     = pk_fp8<true >(pe[1], po[1], w0);
            int w1 = pk_fp8<false>(pe[2], po[2], 0);
            w1     = pk_fp8<true >(pe[3], po[3], w1);
            paL[it] = (i64)(((unsigned long long)(unsigned)w1 << 32) | (unsigned)w0);
        }

        // O += P * V^T ; fp8 MFMA, one b64 V read feeds both i-tiles
        const u8* vb = &vlds[grp][buf][0];
        const i64* vbL = (const i64*)(vb + g * 1024 + li * 8);
        __builtin_amdgcn_s_setprio(1);
#pragma unroll
        for (int cf = 0; cf < 8; ++cf) {
            const i64 vfL = vbL[cf * 16];
            acc[0][cf] = __builtin_amdgcn_mfma_f32_16x16x32_fp8_fp8(paL[0], vfL, acc[0][cf], 0, 0, 0);
            acc[1][cf] = __builtin_amdgcn_mfma_f32_16x16x32_fp8_fp8(paL[1], vfL, acc[1][cf], 0, 0, 0);
        }
        __builtin_amdgcn_s_setprio(0);
        __syncthreads();
        buf ^= 1;
    }

    // ---- merge the 2 j-half partials: pure add (static-max => same scale) ----
#pragma unroll
    for (int it = 0; it < 2; ++it) {
        lsum[it] += __shfl_xor(lsum[it], 16);
        lsum[it] += __shfl_xor(lsum[it], 32);
        lscr[grp][wg][lane][it] = lsum[it];
    }

    f32x4* pv = (f32x4*)&vlds[0][0][0];   // reuse 16 KB as merge scratch
#pragma unroll
    for (int it = 0; it < 2; ++it) {
        __syncthreads();
        if (grp == 1) {
#pragma unroll
            for (int cf = 0; cf < 8; ++cf)
                pv[(wg * 8 + cf) * 64 + lane] = acc[it][cf];
        }
        __syncthreads();
        if (grp == 0) {
#pragma unroll
            for (int cf = 0; cf < 8; ++cf) {
                const f32x4 o4 = pv[(wg * 8 + cf) * 64 + lane];
                acc[it][cf][0] += o4[0]; acc[it][cf][1] += o4[1];
                acc[it][cf][2] += o4[2]; acc[it][cf][3] += o4[3];
            }
        }
    }

    if (grp == 0) {
#pragma unroll
        for (int it = 0; it < 2; ++it) {
            const float linv = 1.0f / (lscr[0][wg][lane][it] + lscr[1][wg][lane][it]);
            float lr[4];
#pragma unroll
            for (int r = 0; r < 4; ++r) lr[r] = __shfl(linv, 4 * g + r);
#pragma unroll
            for (int cf = 0; cf < 8; ++cf)
#pragma unroll
                for (int r = 0; r < 4; ++r)
                    o[(size_t)(i0 + it * 16 + 4 * g + r) * C_DIM + cf * 16 + li] =
                        f2bf(acc[it][cf][r] * lr[r]);
        }
    }
}

// ---------------------------------------------------------------------------
// Kernel 4: out[b][c][i] = x1 + x2 + O1[b][i][c] + O2[b][i][c]  (LDS transpose)
// ---------------------------------------------------------------------------
__global__ __launch_bounds__(256) void epilogue(
    const float* __restrict__ x1, const float* __restrict__ x2,
    const u16* __restrict__ O, float* __restrict__ out)
{
    __shared__ float tl[64][65];
    const int it = blockIdx.x, ct = blockIdx.y, b = blockIdx.z;
    const int tid = threadIdx.x;
    const int cl = tid & 63, r0 = tid >> 6;

    const u16* O1 = O + (size_t)(b)     * N_TOK * C_DIM;
    const u16* O2 = O + (size_t)(4 + b) * N_TOK * C_DIM;

#pragma unroll
    for (int rr = 0; rr < 16; ++rr) {
        const int il = r0 + rr * 4;
        const size_t off = (size_t)(it * 64 + il) * C_DIM + ct * 64 + cl;
        tl[il][cl] = bf2f(O1[off]) + bf2f(O2[off]);
    }
    __syncthreads();
#pragma unroll
    for (int rr = 0; rr < 16; ++rr) {
        const int c2 = r0 + rr * 4;
        const size_t idx = ((size_t)b * C_DIM + ct * 64 + c2) * N_TOK + it * 64 + cl;
        out[idx] = x1[idx] + x2[idx] + tl[cl][c2];
    }
}

// ---------------------------------------------------------------------------
extern "C" void kernel_launch(void* const* d_in, const int* in_sizes, int n_in,
                              void* d_out, int out_size, void* d_ws, size_t ws_size,
                              hipStream_t stream)
{
    const float* x1  = (const float*)d_in[0];
    const float* x2  = (const float*)d_in[1];
    const float* wq1 = (const float*)d_in[2];
    const float* bq1 = (const float*)d_in[3];
    const float* wk1 = (const float*)d_in[4];
    const float* bk1 = (const float*)d_in[5];
    const float* wv1 = (const float*)d_in[6];
    const float* bv1 = (const float*)d_in[7];
    const float* wq2 = (const float*)d_in[8];
    const float* bq2 = (const float*)d_in[9];
    const float* wk2 = (const float*)d_in[10];
    const float* bk2 = (const float*)d_in[11];
    const float* wv2 = (const float*)d_in[12];
    const float* bv2 = (const float*)d_in[13];
    float* out = (float*)d_out;

    // ws layout: Q bf16 2MB | K bf16 2MB | V fp8 packed 8MB | O bf16 16MB
    u16* wsQ = (u16*)d_ws;
    u16* wsK = wsQ + (size_t)8 * N_TOK * D_DIM;
    u8*  wsV = (u8*)(wsK + (size_t)8 * N_TOK * D_DIM);
    u16* wsO = (u16*)(wsV + (size_t)8 * N_TOK * C_DIM);

    qk_proj<<<dim3(64, 16), 256, 0, stream>>>(x1, x2, wq1, bq1, wk1, bk1,
                                              wq2, bq2, wk2, bk2, wsQ, wsK);
    v_proj<<<dim3(32, 2, 8), 256, 0, stream>>>(x2, wv1, bv1, wv2, bv2, wsV);
    attn_fwd<<<dim3(1024), 256, 0, stream>>>(wsQ, wsK, wsV, wsO);
    epilogue<<<dim3(64, 4, 4), 256, 0, stream>>>(x1, x2, wsO, out);
}